// Round 9
// baseline (1550.535 us; speedup 1.0000x reference)
//
#include <hip/hip_runtime.h>
#include <hip/hip_bf16.h>
#include <stdint.h>

#define T_STEPS 16
#define BATCH   16
#define CHANNELS 32
#define HGT 128
#define WID 128
#define HW (HGT*WID)      // 16384
#define KSEL 8192         // ascending 0-based rank of threshold = N - k
#define CAP 1024          // candidate buffer (safety)
#define SMALL 128         // stop narrowing when candidate set <= SMALL
#define NB 4096           // histogram bins
#define NBS 1024.0f       // initial scale: 4096 bins over [0,4)

// DIAGNOSTIC REPEATS (idempotent; removed next round)
#define RPOOL 4
#define RLIF  8
#define RCONV 16

typedef float vfloat4 __attribute__((ext_vector_type(4)));
typedef float vfloat2 __attribute__((ext_vector_type(2)));

__device__ __forceinline__ vfloat4 v4max(vfloat4 a, vfloat4 b) {
    vfloat4 r;
    r.x = fmaxf(a.x, b.x); r.y = fmaxf(a.y, b.y);
    r.z = fmaxf(a.z, b.z); r.w = fmaxf(a.w, b.w);
    return r;
}

__device__ __forceinline__ uint32_t wave_incl_scan(uint32_t v, int lane) {
    #pragma unroll
    for (int off = 1; off < 64; off <<= 1) {
        uint32_t u = __shfl_up(v, off, 64);
        if (lane >= off) v += u;
    }
    return v;
}

__device__ __forceinline__ void lds_barrier() {
    asm volatile("s_waitcnt lgkmcnt(0)" ::: "memory");
    __builtin_amdgcn_s_barrier();
}

// ---------- kernel 1: channel max pool ----------
__global__ __launch_bounds__(256)
void pool_max_kernel(const float* __restrict__ x, float* __restrict__ pooled) {
    int tid  = blockIdx.x * blockDim.x + threadIdx.x;
    int base = tid * 4;
    int tb   = base >> 14;
    int pix  = base & (HW - 1);
    for (int rep = 0; rep < RPOOL; ++rep) {
        const vfloat4* src = (const vfloat4*)(x + (size_t)tb * CHANNELS * HW + pix);
        vfloat4 a0 = src[0 * (HW/4)];
        vfloat4 a1 = src[1 * (HW/4)];
        vfloat4 a2 = src[2 * (HW/4)];
        vfloat4 a3 = src[3 * (HW/4)];
        #pragma unroll
        for (int c = 4; c < CHANNELS; c += 4) {
            a0 = v4max(a0, src[(c+0) * (HW/4)]);
            a1 = v4max(a1, src[(c+1) * (HW/4)]);
            a2 = v4max(a2, src[(c+2) * (HW/4)]);
            a3 = v4max(a3, src[(c+3) * (HW/4)]);
        }
        *(vfloat4*)(pooled + base) = v4max(v4max(a0, a1), v4max(a2, a3));
        asm volatile("" ::: "memory");   // block cross-rep CSE/hoist
    }
}

// ---------- kernel 2: lif0 v4 (raw LDS barriers + prefetch) ----------
__global__ __launch_bounds__(1024)
void lif0_kernel(const float* __restrict__ pooled, uint8_t* __restrict__ spk) {
    __shared__ uint32_t hist[NB];
    __shared__ uint32_t s_wtot[16];
    __shared__ float    col[CAP];
    __shared__ uint32_t s_sel[4];
    __shared__ float    s_thr;

    const int b    = blockIdx.x;
    const int tid  = threadIdx.x;
    const int wid  = tid >> 6;
    const int lane = tid & 63;

    for (int rep = 0; rep < RLIF; ++rep) {
        float m[16];
        #pragma unroll
        for (int i = 0; i < 16; ++i) m[i] = 0.0f;

        hist[tid] = 0; hist[tid + 1024] = 0; hist[tid + 2048] = 0; hist[tid + 3072] = 0;

        const float4* p0 = (const float4*)(pooled + (size_t)b * HW);
        float4 x0 = p0[tid], x1 = p0[1024 + tid], x2 = p0[2048 + tid], x3 = p0[3072 + tid];

        lds_barrier();

        for (int t = 0; t < T_STEPS; ++t) {
            m[ 0] = 0.25f * m[ 0] + x0.x;  m[ 1] = 0.25f * m[ 1] + x0.y;
            m[ 2] = 0.25f * m[ 2] + x0.z;  m[ 3] = 0.25f * m[ 3] + x0.w;
            m[ 4] = 0.25f * m[ 4] + x1.x;  m[ 5] = 0.25f * m[ 5] + x1.y;
            m[ 6] = 0.25f * m[ 6] + x1.z;  m[ 7] = 0.25f * m[ 7] + x1.w;
            m[ 8] = 0.25f * m[ 8] + x2.x;  m[ 9] = 0.25f * m[ 9] + x2.y;
            m[10] = 0.25f * m[10] + x2.z;  m[11] = 0.25f * m[11] + x2.w;
            m[12] = 0.25f * m[12] + x3.x;  m[13] = 0.25f * m[13] + x3.y;
            m[14] = 0.25f * m[14] + x3.z;  m[15] = 0.25f * m[15] + x3.w;

            if (t + 1 < T_STEPS) {
                const float4* pn = (const float4*)(pooled + ((size_t)(t+1) * BATCH + b) * HW);
                x0 = pn[tid]; x1 = pn[1024 + tid]; x2 = pn[2048 + tid]; x3 = pn[3072 + tid];
            }

            float    rlo   = 0.0f;
            float    sc    = NBS;
            uint32_t r     = KSEL;
            uint32_t cnt   = HW;
            uint32_t amask = 0xFFFFu;
            for (int iter = 0;; ++iter) {
                #pragma unroll
                for (int i = 0; i < 16; ++i) {
                    if (amask & (1u << i)) {
                        int bn = (int)((m[i] - rlo) * sc);
                        bn = min(max(bn, 0), NB - 1);
                        atomicAdd(&hist[bn], 1u);
                    }
                }
                lds_barrier();                               // A
                uint4 hc = *(const uint4*)&hist[tid * 4];
                uint4 z; z.x = z.y = z.z = z.w = 0u;
                *(uint4*)&hist[tid * 4] = z;                 // fold clear
                uint32_t psum = hc.x + hc.y + hc.z + hc.w;
                uint32_t incl = wave_incl_scan(psum, lane);
                if (lane == 63) s_wtot[wid] = incl;
                lds_barrier();                               // B
                uint32_t wbase = 0;
                for (int w = 0; w < wid; ++w) wbase += s_wtot[w];
                uint32_t excl = wbase + incl - psum;
                if (tid == 0) s_sel[3] = 0;
                if (r >= excl && r < excl + psum) {
                    uint32_t acc = excl; int dsel = -1; uint32_t nr = 0, nc = 0;
                    if (r < acc + hc.x) { dsel = tid*4+0; nr = r-acc; nc = hc.x; } acc += hc.x;
                    if (dsel < 0 && r < acc + hc.y) { dsel = tid*4+1; nr = r-acc; nc = hc.y; } acc += hc.y;
                    if (dsel < 0 && r < acc + hc.z) { dsel = tid*4+2; nr = r-acc; nc = hc.z; } acc += hc.z;
                    if (dsel < 0 && r < acc + hc.w) { dsel = tid*4+3; nr = r-acc; nc = hc.w; }
                    s_sel[0] = (uint32_t)dsel; s_sel[1] = nr; s_sel[2] = nc;
                }
                lds_barrier();                               // C
                const int jsel = (int)s_sel[0];
                r = s_sel[1]; cnt = s_sel[2];
                uint32_t nm = 0;
                #pragma unroll
                for (int i = 0; i < 16; ++i) {
                    if (amask & (1u << i)) {
                        int bn = (int)((m[i] - rlo) * sc);
                        bn = min(max(bn, 0), NB - 1);
                        if (bn == jsel) nm |= (1u << i);
                    }
                }
                amask = nm;
                rlo += (float)jsel / sc;
                sc  *= (float)NB;
                if (cnt <= SMALL || iter >= 3) break;
            }

            #pragma unroll
            for (int i = 0; i < 16; ++i) {
                if (amask & (1u << i)) {
                    uint32_t u = atomicAdd(&s_sel[3], 1u);
                    if (u < CAP) col[u] = m[i];
                }
            }
            lds_barrier();                                   // D
            {
                uint32_t ncol = min(cnt, (uint32_t)CAP);
                for (uint32_t j = tid; j < ncol; j += 1024) {
                    float v = col[j];
                    uint32_t less = 0, leq = 0;
                    for (uint32_t i2 = 0; i2 < ncol; ++i2) {
                        float u = col[i2];
                        less += (u < v);
                        leq  += (u <= v);
                    }
                    if (less <= r && r < leq) s_thr = v;
                }
            }
            lds_barrier();                                   // E
            const float thr = s_thr;

            uchar4* so4 = (uchar4*)(spk + ((size_t)t * BATCH + b) * HW);
            #pragma unroll
            for (int i = 0; i < 4; ++i) {
                uchar4 s4;
                s4.x = (m[i*4+0] >= thr) ? 1 : 0;
                s4.y = (m[i*4+1] >= thr) ? 1 : 0;
                s4.z = (m[i*4+2] >= thr) ? 1 : 0;
                s4.w = (m[i*4+3] >= thr) ? 1 : 0;
                if (s4.x) m[i*4+0] = 0.0f;
                if (s4.y) m[i*4+1] = 0.0f;
                if (s4.z) m[i*4+2] = 0.0f;
                if (s4.w) m[i*4+3] = 0.0f;
                so4[i * 1024 + tid] = s4;
            }
        }
        asm volatile("" ::: "memory");   // block cross-rep CSE/hoist
        lds_barrier();                   // rep boundary: spike writes done before re-clear
    }
}

// ---------- kernel 3: fused 7x7 conv + lif1 ----------
__global__ __launch_bounds__(256)
void conv_lif1_kernel(const uint8_t* __restrict__ spk, const float* __restrict__ wconv,
                      float* __restrict__ out_spike, float* __restrict__ out_mem) {
    __shared__ float tile[14][136];
    const int bidx   = blockIdx.x;
    const int b      = bidx >> 4;
    const int stripe = bidx & 15;
    const int r0     = stripe * 8;
    const int tid    = threadIdx.x;
    const int sr     = tid >> 5;
    const int c0     = (tid & 31) << 2;

    float w[49];
    #pragma unroll
    for (int i = 0; i < 49; ++i) w[i] = wconv[i];

    for (int rep = 0; rep < RCONV; ++rep) {
        float mem[4] = {0.0f, 0.0f, 0.0f, 0.0f};
        for (int t = 0; t < T_STEPS; ++t) {
            __syncthreads();
            const uint8_t* sp = spk + ((size_t)t * BATCH + b) * HW;
            for (int k = tid; k < 14 * 134; k += 256) {
                int row  = k / 134;
                int colp = k - row * 134;
                int gr = r0 - 3 + row;
                int gc = colp - 3;
                float v = 0.0f;
                if ((unsigned)gr < HGT && (unsigned)gc < WID)
                    v = (float)sp[gr * WID + gc];
                tile[row][colp] = v;
            }
            __syncthreads();
            float a0 = 0.f, a1 = 0.f, a2 = 0.f, a3 = 0.f;
            #pragma unroll
            for (int dy = 0; dy < 7; ++dy) {
                const float* rowp = &tile[sr + dy][c0];
                vfloat4 u = *(const vfloat4*)rowp;
                vfloat4 v = *(const vfloat4*)(rowp + 4);
                vfloat2 e = *(const vfloat2*)(rowp + 8);
                float r[10] = {u.x,u.y,u.z,u.w, v.x,v.y,v.z,v.w, e.x,e.y};
                #pragma unroll
                for (int dx = 0; dx < 7; ++dx) {
                    float wv = w[dy * 7 + dx];
                    a0 = fmaf(r[dx + 0], wv, a0);
                    a1 = fmaf(r[dx + 1], wv, a1);
                    a2 = fmaf(r[dx + 2], wv, a2);
                    a3 = fmaf(r[dx + 3], wv, a3);
                }
            }
            float m0 = 0.25f * mem[0] + a0;
            float m1 = 0.25f * mem[1] + a1;
            float m2 = 0.25f * mem[2] + a2;
            float m3 = 0.25f * mem[3] + a3;
            float s0 = (m0 > 1.0f) ? 1.0f : 0.0f;
            float s1 = (m1 > 1.0f) ? 1.0f : 0.0f;
            float s2 = (m2 > 1.0f) ? 1.0f : 0.0f;
            float s3 = (m3 > 1.0f) ? 1.0f : 0.0f;
            size_t o = (((size_t)t * BATCH + b) << 14) + (size_t)(r0 + sr) * WID + c0;
            vfloat4 sv = {s0, s1, s2, s3};
            vfloat4 mv = {m0, m1, m2, m3};
            *(vfloat4*)(out_spike + o) = sv;
            *(vfloat4*)(out_mem   + o) = mv;
            mem[0] = m0 - s0; mem[1] = m1 - s1; mem[2] = m2 - s2; mem[3] = m3 - s3;
        }
        asm volatile("" ::: "memory");   // block cross-rep CSE/hoist
        __syncthreads();                 // rep boundary
    }
}

extern "C" void kernel_launch(void* const* d_in, const int* in_sizes, int n_in,
                              void* d_out, int out_size, void* d_ws, size_t ws_size,
                              hipStream_t stream) {
    const float* x     = (const float*)d_in[0];
    const float* wconv = (const float*)d_in[1];
    float* out = (float*)d_out;

    const size_t n_pooled = (size_t)T_STEPS * BATCH * HW;
    float*   pooled = (float*)d_ws;
    uint8_t* spk    = (uint8_t*)d_ws + n_pooled * sizeof(float);

    pool_max_kernel<<<4096, 256, 0, stream>>>(x, pooled);
    lif0_kernel<<<BATCH, 1024, 0, stream>>>(pooled, spk);
    conv_lif1_kernel<<<256, 256, 0, stream>>>(spk, wconv, out, out + n_pooled);
}

// Round 10
// 240.988 us; speedup vs baseline: 6.4341x; 6.4341x over previous
//
#include <hip/hip_runtime.h>
#include <hip/hip_bf16.h>
#include <stdint.h>

#define T_STEPS 16
#define BATCH   16
#define CHANNELS 32
#define HGT 128
#define WID 128
#define HW (HGT*WID)      // 16384
#define KSEL 8192         // ascending 0-based rank of threshold = N - k
#define CAP 1024          // candidate buffer (safety)
#define SMALL 128         // stop narrowing when candidate set <= SMALL
#define NB 4096           // histogram bins
#define NBS 1024.0f       // initial scale: 4096 bins over [0,4)

typedef float vfloat4 __attribute__((ext_vector_type(4)));

__device__ __forceinline__ vfloat4 v4max(vfloat4 a, vfloat4 b) {
    vfloat4 r;
    r.x = fmaxf(a.x, b.x); r.y = fmaxf(a.y, b.y);
    r.z = fmaxf(a.z, b.z); r.w = fmaxf(a.w, b.w);
    return r;
}

__device__ __forceinline__ uint32_t wave_incl_scan(uint32_t v, int lane) {
    #pragma unroll
    for (int off = 1; off < 64; off <<= 1) {
        uint32_t u = __shfl_up(v, off, 64);
        if (lane >= off) v += u;
    }
    return v;
}

// LDS-only barrier: drain DS ops, keep global prefetch loads in flight.
__device__ __forceinline__ void lds_barrier() {
    asm volatile("s_waitcnt lgkmcnt(0)" ::: "memory");
    __builtin_amdgcn_s_barrier();
}

// ---------- kernel 1: channel max pool (unchanged, P ~ 115 us) ----------
__global__ __launch_bounds__(256)
void pool_max_kernel(const float* __restrict__ x, float* __restrict__ pooled) {
    int tid  = blockIdx.x * blockDim.x + threadIdx.x;
    int base = tid * 4;
    int tb   = base >> 14;
    int pix  = base & (HW - 1);
    const vfloat4* src = (const vfloat4*)(x + (size_t)tb * CHANNELS * HW + pix);
    vfloat4 a0 = src[0 * (HW/4)];
    vfloat4 a1 = src[1 * (HW/4)];
    vfloat4 a2 = src[2 * (HW/4)];
    vfloat4 a3 = src[3 * (HW/4)];
    #pragma unroll
    for (int c = 4; c < CHANNELS; c += 4) {
        a0 = v4max(a0, src[(c+0) * (HW/4)]);
        a1 = v4max(a1, src[(c+1) * (HW/4)]);
        a2 = v4max(a2, src[(c+2) * (HW/4)]);
        a3 = v4max(a3, src[(c+3) * (HW/4)]);
    }
    *(vfloat4*)(pooled + base) = v4max(v4max(a0, a1), v4max(a2, a3));
}

// ---------- kernel 2: lif0 v4 (unchanged, L ~ 31-40 us) ----------
__global__ __launch_bounds__(1024)
void lif0_kernel(const float* __restrict__ pooled, uint8_t* __restrict__ spk) {
    __shared__ uint32_t hist[NB];
    __shared__ uint32_t s_wtot[16];
    __shared__ float    col[CAP];
    __shared__ uint32_t s_sel[4];
    __shared__ float    s_thr;

    const int b    = blockIdx.x;
    const int tid  = threadIdx.x;
    const int wid  = tid >> 6;
    const int lane = tid & 63;

    float m[16];
    #pragma unroll
    for (int i = 0; i < 16; ++i) m[i] = 0.0f;

    hist[tid] = 0; hist[tid + 1024] = 0; hist[tid + 2048] = 0; hist[tid + 3072] = 0;

    const float4* p0 = (const float4*)(pooled + (size_t)b * HW);
    float4 x0 = p0[tid], x1 = p0[1024 + tid], x2 = p0[2048 + tid], x3 = p0[3072 + tid];

    lds_barrier();

    for (int t = 0; t < T_STEPS; ++t) {
        m[ 0] = 0.25f * m[ 0] + x0.x;  m[ 1] = 0.25f * m[ 1] + x0.y;
        m[ 2] = 0.25f * m[ 2] + x0.z;  m[ 3] = 0.25f * m[ 3] + x0.w;
        m[ 4] = 0.25f * m[ 4] + x1.x;  m[ 5] = 0.25f * m[ 5] + x1.y;
        m[ 6] = 0.25f * m[ 6] + x1.z;  m[ 7] = 0.25f * m[ 7] + x1.w;
        m[ 8] = 0.25f * m[ 8] + x2.x;  m[ 9] = 0.25f * m[ 9] + x2.y;
        m[10] = 0.25f * m[10] + x2.z;  m[11] = 0.25f * m[11] + x2.w;
        m[12] = 0.25f * m[12] + x3.x;  m[13] = 0.25f * m[13] + x3.y;
        m[14] = 0.25f * m[14] + x3.z;  m[15] = 0.25f * m[15] + x3.w;

        if (t + 1 < T_STEPS) {
            const float4* pn = (const float4*)(pooled + ((size_t)(t+1) * BATCH + b) * HW);
            x0 = pn[tid]; x1 = pn[1024 + tid]; x2 = pn[2048 + tid]; x3 = pn[3072 + tid];
        }

        float    rlo   = 0.0f;
        float    sc    = NBS;
        uint32_t r     = KSEL;
        uint32_t cnt   = HW;
        uint32_t amask = 0xFFFFu;
        for (int iter = 0;; ++iter) {
            #pragma unroll
            for (int i = 0; i < 16; ++i) {
                if (amask & (1u << i)) {
                    int bn = (int)((m[i] - rlo) * sc);
                    bn = min(max(bn, 0), NB - 1);
                    atomicAdd(&hist[bn], 1u);
                }
            }
            lds_barrier();                               // A
            uint4 hc = *(const uint4*)&hist[tid * 4];
            uint4 z; z.x = z.y = z.z = z.w = 0u;
            *(uint4*)&hist[tid * 4] = z;                 // fold clear
            uint32_t psum = hc.x + hc.y + hc.z + hc.w;
            uint32_t incl = wave_incl_scan(psum, lane);
            if (lane == 63) s_wtot[wid] = incl;
            lds_barrier();                               // B
            uint32_t wbase = 0;
            for (int w = 0; w < wid; ++w) wbase += s_wtot[w];
            uint32_t excl = wbase + incl - psum;
            if (tid == 0) s_sel[3] = 0;
            if (r >= excl && r < excl + psum) {
                uint32_t acc = excl; int dsel = -1; uint32_t nr = 0, nc = 0;
                if (r < acc + hc.x) { dsel = tid*4+0; nr = r-acc; nc = hc.x; } acc += hc.x;
                if (dsel < 0 && r < acc + hc.y) { dsel = tid*4+1; nr = r-acc; nc = hc.y; } acc += hc.y;
                if (dsel < 0 && r < acc + hc.z) { dsel = tid*4+2; nr = r-acc; nc = hc.z; } acc += hc.z;
                if (dsel < 0 && r < acc + hc.w) { dsel = tid*4+3; nr = r-acc; nc = hc.w; }
                s_sel[0] = (uint32_t)dsel; s_sel[1] = nr; s_sel[2] = nc;
            }
            lds_barrier();                               // C
            const int jsel = (int)s_sel[0];
            r = s_sel[1]; cnt = s_sel[2];
            uint32_t nm = 0;
            #pragma unroll
            for (int i = 0; i < 16; ++i) {
                if (amask & (1u << i)) {
                    int bn = (int)((m[i] - rlo) * sc);
                    bn = min(max(bn, 0), NB - 1);
                    if (bn == jsel) nm |= (1u << i);
                }
            }
            amask = nm;
            rlo += (float)jsel / sc;
            sc  *= (float)NB;
            if (cnt <= SMALL || iter >= 3) break;
        }

        #pragma unroll
        for (int i = 0; i < 16; ++i) {
            if (amask & (1u << i)) {
                uint32_t u = atomicAdd(&s_sel[3], 1u);
                if (u < CAP) col[u] = m[i];
            }
        }
        lds_barrier();                                   // D
        {
            uint32_t ncol = min(cnt, (uint32_t)CAP);
            for (uint32_t j = tid; j < ncol; j += 1024) {
                float v = col[j];
                uint32_t less = 0, leq = 0;
                for (uint32_t i2 = 0; i2 < ncol; ++i2) {
                    float u = col[i2];
                    less += (u < v);
                    leq  += (u <= v);
                }
                if (less <= r && r < leq) s_thr = v;     // k-th largest, exact bits
            }
        }
        lds_barrier();                                   // E
        const float thr = s_thr;

        uchar4* so4 = (uchar4*)(spk + ((size_t)t * BATCH + b) * HW);
        #pragma unroll
        for (int i = 0; i < 4; ++i) {
            uchar4 s4;
            s4.x = (m[i*4+0] >= thr) ? 1 : 0;
            s4.y = (m[i*4+1] >= thr) ? 1 : 0;
            s4.z = (m[i*4+2] >= thr) ? 1 : 0;
            s4.w = (m[i*4+3] >= thr) ? 1 : 0;
            if (s4.x) m[i*4+0] = 0.0f;
            if (s4.y) m[i*4+1] = 0.0f;
            if (s4.z) m[i*4+2] = 0.0f;
            if (s4.w) m[i*4+3] = 0.0f;
            so4[i * 1024 + tid] = s4;
        }
    }
}

// ---------- kernel 3: conv v3 — 1024 blocks, scalar conflict-free reads ----------
// 2-row stripes: 4 blocks/CU, 16 waves/CU (was 1 wave/SIMD). 1 px/thread;
// lanes read consecutive tile cols -> 2-way bank aliasing = free (m136).
__global__ __launch_bounds__(256)
void conv_lif1_kernel(const uint8_t* __restrict__ spk, const float* __restrict__ wconv,
                      float* __restrict__ out_spike, float* __restrict__ out_mem) {
    __shared__ float tile[8][136];   // 2-row stripe + 3 halo each side
    const int bidx   = blockIdx.x;   // 0..1023
    const int b      = bidx >> 6;
    const int stripe = bidx & 63;
    const int r0     = stripe * 2;
    const int tid    = threadIdx.x;
    const int lr     = tid >> 7;     // 0..1
    const int lc     = tid & 127;

    float w[49];
    #pragma unroll
    for (int i = 0; i < 49; ++i) w[i] = wconv[i];   // uniform -> scalar regs

    float mem = 0.0f;

    for (int t = 0; t < T_STEPS; ++t) {
        __syncthreads();   // tile reuse guard
        const uint8_t* sp = spk + ((size_t)t * BATCH + b) * HW;
        for (int k = tid; k < 8 * 134; k += 256) {
            int row  = k / 134;
            int colp = k - row * 134;
            int gr = r0 - 3 + row;
            int gc = colp - 3;
            float v = 0.0f;
            if ((unsigned)gr < HGT && (unsigned)gc < WID)
                v = (float)sp[gr * WID + gc];
            tile[row][colp] = v;
        }
        __syncthreads();
        float acc = 0.0f;
        #pragma unroll
        for (int dy = 0; dy < 7; ++dy)
            #pragma unroll
            for (int dx = 0; dx < 7; ++dx)
                acc = fmaf(tile[lr + dy][lc + dx], w[dy * 7 + dx], acc);
        float mm  = 0.25f * mem + acc;
        float sp2 = (mm > 1.0f) ? 1.0f : 0.0f;
        size_t o = (((size_t)t * BATCH + b) << 14) + (size_t)(r0 + lr) * WID + lc;
        out_spike[o] = sp2;
        out_mem[o]   = mm;
        mem = mm - sp2;      // soft reset
    }
}

extern "C" void kernel_launch(void* const* d_in, const int* in_sizes, int n_in,
                              void* d_out, int out_size, void* d_ws, size_t ws_size,
                              hipStream_t stream) {
    const float* x     = (const float*)d_in[0];
    const float* wconv = (const float*)d_in[1];
    float* out = (float*)d_out;

    const size_t n_pooled = (size_t)T_STEPS * BATCH * HW;
    float*   pooled = (float*)d_ws;
    uint8_t* spk    = (uint8_t*)d_ws + n_pooled * sizeof(float);

    pool_max_kernel<<<4096, 256, 0, stream>>>(x, pooled);
    lif0_kernel<<<BATCH, 1024, 0, stream>>>(pooled, spk);
    conv_lif1_kernel<<<BATCH * 64, 256, 0, stream>>>(spk, wconv, out, out + n_pooled);
}

// Round 11
// 224.456 us; speedup vs baseline: 6.9080x; 1.0737x over previous
//
#include <hip/hip_runtime.h>
#include <hip/hip_bf16.h>
#include <stdint.h>

#define T_STEPS 16
#define BATCH   16
#define CHANNELS 32
#define HGT 128
#define WID 128
#define HW (HGT*WID)      // 16384
#define KSEL 8192         // ascending 0-based rank of threshold = N - k
#define CAP 1024          // candidate buffer (safety)
#define SMALL 128         // stop narrowing when candidate set <= SMALL
#define NB 4096           // histogram bins
#define NBS 1024.0f       // initial scale: 4096 bins over [0,4)

typedef float vfloat4 __attribute__((ext_vector_type(4)));

__device__ __forceinline__ vfloat4 v4max(vfloat4 a, vfloat4 b) {
    vfloat4 r;
    r.x = fmaxf(a.x, b.x); r.y = fmaxf(a.y, b.y);
    r.z = fmaxf(a.z, b.z); r.w = fmaxf(a.w, b.w);
    return r;
}

__device__ __forceinline__ uint32_t wave_incl_scan(uint32_t v, int lane) {
    #pragma unroll
    for (int off = 1; off < 64; off <<= 1) {
        uint32_t u = __shfl_up(v, off, 64);
        if (lane >= off) v += u;
    }
    return v;
}

// LDS-only barrier: drain DS ops, keep global loads in flight.
__device__ __forceinline__ void lds_barrier() {
    asm volatile("s_waitcnt lgkmcnt(0)" ::: "memory");
    __builtin_amdgcn_s_barrier();
}

// ---------- kernel 1: channel max pool — NT loads (118 us measured r5) ----------
// NT avoids evicting L2/L3 with a 512 MB never-reused stream.
__global__ __launch_bounds__(256)
void pool_max_kernel(const float* __restrict__ x, float* __restrict__ pooled) {
    int tid  = blockIdx.x * blockDim.x + threadIdx.x;
    int base = tid * 4;
    int tb   = base >> 14;
    int pix  = base & (HW - 1);
    const vfloat4* src = (const vfloat4*)(x + (size_t)tb * CHANNELS * HW + pix);
    vfloat4 a0 = __builtin_nontemporal_load(src + 0 * (HW/4));
    vfloat4 a1 = __builtin_nontemporal_load(src + 1 * (HW/4));
    vfloat4 a2 = __builtin_nontemporal_load(src + 2 * (HW/4));
    vfloat4 a3 = __builtin_nontemporal_load(src + 3 * (HW/4));
    #pragma unroll
    for (int c = 4; c < CHANNELS; c += 4) {
        a0 = v4max(a0, __builtin_nontemporal_load(src + (size_t)(c+0) * (HW/4)));
        a1 = v4max(a1, __builtin_nontemporal_load(src + (size_t)(c+1) * (HW/4)));
        a2 = v4max(a2, __builtin_nontemporal_load(src + (size_t)(c+2) * (HW/4)));
        a3 = v4max(a3, __builtin_nontemporal_load(src + (size_t)(c+3) * (HW/4)));
    }
    *(vfloat4*)(pooled + base) = v4max(v4max(a0, a1), v4max(a2, a3));
}

// ---------- kernel 2: lif0 v4 (unchanged; at 16-CU BW floor ~40 us) ----------
__global__ __launch_bounds__(1024)
void lif0_kernel(const float* __restrict__ pooled, uint8_t* __restrict__ spk) {
    __shared__ uint32_t hist[NB];
    __shared__ uint32_t s_wtot[16];
    __shared__ float    col[CAP];
    __shared__ uint32_t s_sel[4];
    __shared__ float    s_thr;

    const int b    = blockIdx.x;
    const int tid  = threadIdx.x;
    const int wid  = tid >> 6;
    const int lane = tid & 63;

    float m[16];
    #pragma unroll
    for (int i = 0; i < 16; ++i) m[i] = 0.0f;

    hist[tid] = 0; hist[tid + 1024] = 0; hist[tid + 2048] = 0; hist[tid + 3072] = 0;

    const float4* p0 = (const float4*)(pooled + (size_t)b * HW);
    float4 x0 = p0[tid], x1 = p0[1024 + tid], x2 = p0[2048 + tid], x3 = p0[3072 + tid];

    lds_barrier();

    for (int t = 0; t < T_STEPS; ++t) {
        m[ 0] = 0.25f * m[ 0] + x0.x;  m[ 1] = 0.25f * m[ 1] + x0.y;
        m[ 2] = 0.25f * m[ 2] + x0.z;  m[ 3] = 0.25f * m[ 3] + x0.w;
        m[ 4] = 0.25f * m[ 4] + x1.x;  m[ 5] = 0.25f * m[ 5] + x1.y;
        m[ 6] = 0.25f * m[ 6] + x1.z;  m[ 7] = 0.25f * m[ 7] + x1.w;
        m[ 8] = 0.25f * m[ 8] + x2.x;  m[ 9] = 0.25f * m[ 9] + x2.y;
        m[10] = 0.25f * m[10] + x2.z;  m[11] = 0.25f * m[11] + x2.w;
        m[12] = 0.25f * m[12] + x3.x;  m[13] = 0.25f * m[13] + x3.y;
        m[14] = 0.25f * m[14] + x3.z;  m[15] = 0.25f * m[15] + x3.w;

        if (t + 1 < T_STEPS) {
            const float4* pn = (const float4*)(pooled + ((size_t)(t+1) * BATCH + b) * HW);
            x0 = pn[tid]; x1 = pn[1024 + tid]; x2 = pn[2048 + tid]; x3 = pn[3072 + tid];
        }

        float    rlo   = 0.0f;
        float    sc    = NBS;
        uint32_t r     = KSEL;
        uint32_t cnt   = HW;
        uint32_t amask = 0xFFFFu;
        for (int iter = 0;; ++iter) {
            #pragma unroll
            for (int i = 0; i < 16; ++i) {
                if (amask & (1u << i)) {
                    int bn = (int)((m[i] - rlo) * sc);
                    bn = min(max(bn, 0), NB - 1);
                    atomicAdd(&hist[bn], 1u);
                }
            }
            lds_barrier();                               // A
            uint4 hc = *(const uint4*)&hist[tid * 4];
            uint4 z; z.x = z.y = z.z = z.w = 0u;
            *(uint4*)&hist[tid * 4] = z;                 // fold clear
            uint32_t psum = hc.x + hc.y + hc.z + hc.w;
            uint32_t incl = wave_incl_scan(psum, lane);
            if (lane == 63) s_wtot[wid] = incl;
            lds_barrier();                               // B
            uint32_t wbase = 0;
            for (int w = 0; w < wid; ++w) wbase += s_wtot[w];
            uint32_t excl = wbase + incl - psum;
            if (tid == 0) s_sel[3] = 0;
            if (r >= excl && r < excl + psum) {
                uint32_t acc = excl; int dsel = -1; uint32_t nr = 0, nc = 0;
                if (r < acc + hc.x) { dsel = tid*4+0; nr = r-acc; nc = hc.x; } acc += hc.x;
                if (dsel < 0 && r < acc + hc.y) { dsel = tid*4+1; nr = r-acc; nc = hc.y; } acc += hc.y;
                if (dsel < 0 && r < acc + hc.z) { dsel = tid*4+2; nr = r-acc; nc = hc.z; } acc += hc.z;
                if (dsel < 0 && r < acc + hc.w) { dsel = tid*4+3; nr = r-acc; nc = hc.w; }
                s_sel[0] = (uint32_t)dsel; s_sel[1] = nr; s_sel[2] = nc;
            }
            lds_barrier();                               // C
            const int jsel = (int)s_sel[0];
            r = s_sel[1]; cnt = s_sel[2];
            uint32_t nm = 0;
            #pragma unroll
            for (int i = 0; i < 16; ++i) {
                if (amask & (1u << i)) {
                    int bn = (int)((m[i] - rlo) * sc);
                    bn = min(max(bn, 0), NB - 1);
                    if (bn == jsel) nm |= (1u << i);
                }
            }
            amask = nm;
            rlo += (float)jsel / sc;
            sc  *= (float)NB;
            if (cnt <= SMALL || iter >= 3) break;
        }

        #pragma unroll
        for (int i = 0; i < 16; ++i) {
            if (amask & (1u << i)) {
                uint32_t u = atomicAdd(&s_sel[3], 1u);
                if (u < CAP) col[u] = m[i];
            }
        }
        lds_barrier();                                   // D
        {
            uint32_t ncol = min(cnt, (uint32_t)CAP);
            for (uint32_t j = tid; j < ncol; j += 1024) {
                float v = col[j];
                uint32_t less = 0, leq = 0;
                for (uint32_t i2 = 0; i2 < ncol; ++i2) {
                    float u = col[i2];
                    less += (u < v);
                    leq  += (u <= v);
                }
                if (less <= r && r < leq) s_thr = v;     // k-th largest, exact bits
            }
        }
        lds_barrier();                                   // E
        const float thr = s_thr;

        uchar4* so4 = (uchar4*)(spk + ((size_t)t * BATCH + b) * HW);
        #pragma unroll
        for (int i = 0; i < 4; ++i) {
            uchar4 s4;
            s4.x = (m[i*4+0] >= thr) ? 1 : 0;
            s4.y = (m[i*4+1] >= thr) ? 1 : 0;
            s4.z = (m[i*4+2] >= thr) ? 1 : 0;
            s4.w = (m[i*4+3] >= thr) ? 1 : 0;
            if (s4.x) m[i*4+0] = 0.0f;
            if (s4.y) m[i*4+1] = 0.0f;
            if (s4.z) m[i*4+2] = 0.0f;
            if (s4.w) m[i*4+3] = 0.0f;
            so4[i * 1024 + tid] = s4;
        }
    }
}

// ---------- kernel 3: conv v5 — 4-timestep chunks, double-buffered LDS ----------
// 1024 blocks (b x 2-row stripe), 256 thr. 5 barriers total (was 32); chunk
// c+1's global loads issued before chunk c's compute -> latency hidden (T14).
#define CHUNK_ELEMS (4 * 8 * 134)   // 4288
__global__ __launch_bounds__(256)
void conv_lif1_kernel(const uint8_t* __restrict__ spk, const float* __restrict__ wconv,
                      float* __restrict__ out_spike, float* __restrict__ out_mem) {
    __shared__ float tile[2][4][8][136];   // dbuf x tt x row x col-pad = 34 KB
    const int bidx   = blockIdx.x;         // 0..1023
    const int b      = bidx >> 6;
    const int stripe = bidx & 63;
    const int r0     = stripe * 2;
    const int tid    = threadIdx.x;
    const int lr     = tid >> 7;           // 0..1
    const int lc     = tid & 127;

    float w[49];
    #pragma unroll
    for (int i = 0; i < 49; ++i) w[i] = wconv[i];

    // stage chunk 0 (t = 0..3) directly
    for (int k = tid; k < CHUNK_ELEMS; k += 256) {
        int tt   = k / (8 * 134);
        int rem  = k - tt * (8 * 134);
        int row  = rem / 134;
        int colp = rem - row * 134;
        int gr = r0 - 3 + row;
        int gc = colp - 3;
        float v = 0.0f;
        if ((unsigned)gr < HGT && (unsigned)gc < WID)
            v = (float)spk[(((size_t)tt * BATCH + b) << 14) + gr * WID + gc];
        tile[0][tt][row][colp] = v;
    }

    float mem = 0.0f;
    for (int c = 0; c < 4; ++c) {
        lds_barrier();   // buf[c&1] fully written; prior readers of buf[(c+1)&1] done
        // issue global loads for chunk c+1 (stay in flight through compute)
        float stg[17];
        if (c < 3) {
            #pragma unroll
            for (int j = 0; j < 17; ++j) {
                int k = tid + j * 256;
                float v = 0.0f;
                if (k < CHUNK_ELEMS) {
                    int tt   = k / (8 * 134);
                    int rem  = k - tt * (8 * 134);
                    int row  = rem / 134;
                    int colp = rem - row * 134;
                    int gr = r0 - 3 + row;
                    int gc = colp - 3;
                    if ((unsigned)gr < HGT && (unsigned)gc < WID)
                        v = (float)spk[(((size_t)((c+1)*4 + tt) * BATCH + b) << 14) + gr * WID + gc];
                }
                stg[j] = v;
            }
        }
        // compute 4 timesteps from buf[c&1]
        #pragma unroll
        for (int tt = 0; tt < 4; ++tt) {
            float acc = 0.0f;
            #pragma unroll
            for (int dy = 0; dy < 7; ++dy)
                #pragma unroll
                for (int dx = 0; dx < 7; ++dx)
                    acc = fmaf(tile[c & 1][tt][lr + dy][lc + dx], w[dy * 7 + dx], acc);
            float mm  = 0.25f * mem + acc;
            float sp2 = (mm > 1.0f) ? 1.0f : 0.0f;
            int t = c * 4 + tt;
            size_t o = (((size_t)t * BATCH + b) << 14) + (size_t)(r0 + lr) * WID + lc;
            out_spike[o] = sp2;
            out_mem[o]   = mm;
            mem = mm - sp2;   // soft reset
        }
        // write staged regs into buf[(c+1)&1] (its old readers finished pre-barrier)
        if (c < 3) {
            #pragma unroll
            for (int j = 0; j < 17; ++j) {
                int k = tid + j * 256;
                if (k < CHUNK_ELEMS) {
                    int tt   = k / (8 * 134);
                    int rem  = k - tt * (8 * 134);
                    int row  = rem / 134;
                    int colp = rem - row * 134;
                    tile[(c + 1) & 1][tt][row][colp] = stg[j];
                }
            }
        }
    }
}

extern "C" void kernel_launch(void* const* d_in, const int* in_sizes, int n_in,
                              void* d_out, int out_size, void* d_ws, size_t ws_size,
                              hipStream_t stream) {
    const float* x     = (const float*)d_in[0];
    const float* wconv = (const float*)d_in[1];
    float* out = (float*)d_out;

    const size_t n_pooled = (size_t)T_STEPS * BATCH * HW;
    float*   pooled = (float*)d_ws;
    uint8_t* spk    = (uint8_t*)d_ws + n_pooled * sizeof(float);

    pool_max_kernel<<<4096, 256, 0, stream>>>(x, pooled);
    lif0_kernel<<<BATCH, 1024, 0, stream>>>(pooled, spk);
    conv_lif1_kernel<<<BATCH * 64, 256, 0, stream>>>(spk, wconv, out, out + n_pooled);
}